// Round 13
// baseline (74.464 us; speedup 1.0000x reference)
//
#include <hip/hip_runtime.h>

// RBF-MMD discriminator: B=512 rows, T=128 slabs, C=16, fp32.
// out = E_xx - 2*E_xy over per-slab RBF grams (slab weight 1 for t in {0,127},
// else 2; 254 weighted slab instances).
//
// R13 structure: R11/R12 decomposition — compute ~5us, in-kernel F ~19us
// invariant to block count & structure. Common factor: staging reads are
// 64B-granular scattered lines (rows 2KB apart), ~22.5MB FETCH at ~1.1TB/s
// effective = F. Fix the GRANULARITY: block = (a,q) pair x 4 consecutive t's;
// each thread reads its row's 4-slab chunk as 256B CONTIGUOUS (4 fully-used
// lines), converts all 4 slabs, ONE barrier, then 4 uninterrupted compute
// passes. Grid (26,32)=832, 47KB LDS -> 3 blocks/CU.
//
// Numerics = R8/R11/R12 (absmax 0.0): pure-bf16 dot via 16x16x32 MFMA,
// column norm folded into free K-slots (k16,k17 = -g_col hi/lo vs A=1.0),
// acc = log2e*(dot - |col|^2/2); per-entry work = exp2 + add.
// Row-scale 2^-g_row (+ slab weight) in epilogue; diagonal subtracted in
// finalize. Kxx symmetry: strip-pairs q>=a only, q>a weighted 2x (exact).

#define LOG2E 1.4426950408889634f
#define SCALE 1.2011224087864498f   // sqrt(LOG2E)
#define NSLOT 26
#define ONEONE 0x3F803F80u          // packed bf16 {1.0, 1.0}

typedef __attribute__((ext_vector_type(8))) __bf16 bf16x8;
typedef __attribute__((ext_vector_type(4))) float floatx4;

union FragU { uint4 q; unsigned int u[4]; bf16x8 v; };

// 16B-aligned group-padded LDS row offset (dwords): 8 dw/row + 4 dw pad per 4 rows.
static __device__ __forceinline__ int off(int n) { return (n << 3) + ((n >> 2) << 2); }

static __device__ __forceinline__ unsigned short bfbits(__bf16 h) {
    union { __bf16 h; unsigned short s; } u; u.h = h; return u.s;
}
static __device__ __forceinline__ unsigned int packhh(__bf16 a, __bf16 b) {
    return (unsigned int)bfbits(a) | ((unsigned int)bfbits(b) << 16);
}
static __device__ __forceinline__ unsigned int packff(float a, float b) {
    return packhh((__bf16)(a * SCALE), (__bf16)(b * SCALE));
}

// spill-proof one-slab conversion (named scalars, by-value) — from R10.
static __device__ __forceinline__ void stage_row(int half, int r,
                                                 float4 f0, float4 f1,
                                                 float4 f2, float4 f3,
                                                 unsigned int* __restrict__ AHb,
                                                 unsigned int* __restrict__ BHb,
                                                 unsigned int* __restrict__ BGb,
                                                 float* __restrict__ srgb) {
    const float g =
        (f0.x * f0.x + f0.y * f0.y + f0.z * f0.z + f0.w * f0.w) +
        (f1.x * f1.x + f1.y * f1.y + f1.z * f1.z + f1.w * f1.w) +
        (f2.x * f2.x + f2.y * f2.y + f2.z * f2.z + f2.w * f2.w) +
        (f3.x * f3.x + f3.y * f3.y + f3.z * f3.z + f3.w * f3.w);
    unsigned int* __restrict__ H = half ? BHb : AHb;
    const int o = off(r);
    *(uint4*)&H[o]     = make_uint4(packff(f0.x, f0.y), packff(f0.z, f0.w),
                                    packff(f1.x, f1.y), packff(f1.z, f1.w));
    *(uint4*)&H[o + 4] = make_uint4(packff(f2.x, f2.y), packff(f2.z, f2.w),
                                    packff(f3.x, f3.y), packff(f3.z, f3.w));
    const float gp = 0.5f * LOG2E * g;
    if (half) {
        const __bf16 nh = (__bf16)(-gp);
        const __bf16 nl = (__bf16)(-(gp + (float)nh));
        *(uint4*)&BGb[r * 4] = make_uint4(packhh(nh, nl), 0u, 0u, 0u);
    } else {
        srgb[r] = gp;
    }
}

// grid (26,32): blockIdx.x = pair slot, blockIdx.y = t-group (4 t's).
// slot<16: xy, a=slot>>2 (A strip of X), q=slot&3 (col strip of Y).
// slot>=16: xx triangular (a,q), q>=a, weight 2 if q>a.
// 4 waves; wave w owns A rows a*128 + w*32 (two 16-row tiles).
__global__ __launch_bounds__(256, 3) void mmd_kernel(const float* __restrict__ x,
                                                     const float* __restrict__ y,
                                                     float* __restrict__ part) {
    __shared__ unsigned int AH[4][1152], BH[4][1152];
    __shared__ unsigned int BG[4][512];   // per B-row: {pack(-ghi,-glo),0,0,0}
    __shared__ float srg[4][128];         // g per A-row
    __shared__ unsigned int zero4[4];
    __shared__ float red[4];

    const int slot = blockIdx.x;
    const int tg   = blockIdx.y;          // t = tg*4 + tt
    const int tid  = threadIdx.x;
    const int w    = tid >> 6;
    const int lane = tid & 63;
    const int quad = lane >> 4;
    const int l15  = lane & 15;
    const int qh   = quad & 1;

    int sa, sq, isxx;
    if (slot < 16) { isxx = 0; sa = slot >> 2; sq = slot & 3; }
    else {
        isxx = 1;
        const int s = slot - 16;
        if      (s < 4) { sa = 0; sq = s; }
        else if (s < 7) { sa = 1; sq = s - 3; }
        else if (s < 9) { sa = 2; sq = s - 5; }
        else            { sa = 3; sq = 3; }
    }

    if (tid == 0) { zero4[0] = 0u; zero4[1] = 0u; zero4[2] = 0u; zero4[3] = 0u; }

    // ---- staging: ONE contiguous 256B read per thread covers 4 slabs ----
    {
        const int half = tid >> 7;
        const int r    = tid & 127;
        const float4* __restrict__ src4 =
            (half && !isxx) ? (const float4*)y : (const float4*)x;
        const size_t gb = (size_t)((half ? sq : sa) * 128 + r) * 512 + (size_t)tg * 16;
        const float4 c0  = src4[gb],      c1  = src4[gb + 1],
                     c2  = src4[gb + 2],  c3  = src4[gb + 3];
        const float4 c4  = src4[gb + 4],  c5  = src4[gb + 5],
                     c6  = src4[gb + 6],  c7  = src4[gb + 7];
        const float4 c8  = src4[gb + 8],  c9  = src4[gb + 9],
                     c10 = src4[gb + 10], c11 = src4[gb + 11];
        const float4 c12 = src4[gb + 12], c13 = src4[gb + 13],
                     c14 = src4[gb + 14], c15 = src4[gb + 15];
        stage_row(half, r, c0,  c1,  c2,  c3,  AH[0], BH[0], BG[0], srg[0]);
        stage_row(half, r, c4,  c5,  c6,  c7,  AH[1], BH[1], BG[1], srg[1]);
        stage_row(half, r, c8,  c9,  c10, c11, AH[2], BH[2], BG[2], srg[2]);
        stage_row(half, r, c12, c13, c14, c15, AH[3], BH[3], BG[3], srg[3]);
    }
    __syncthreads();

    float tot = 0.f;

    // ---- 4 uninterrupted compute passes (R8's verified loop per t) ----
#pragma unroll 1
    for (int tt = 0; tt < 4; ++tt) {
        const int t = tg * 4 + tt;

        // A fragments for this slab
        bf16x8 a1f0, a1f1;
        {
            FragU u0, u1;
            if (quad < 2) {
                const int r0 = w * 32 + l15;
                u0.q = *(const uint4*)&AH[tt][off(r0) + qh * 4];
                u1.q = *(const uint4*)&AH[tt][off(r0 + 16) + qh * 4];
            } else {
                u0.q = make_uint4((quad == 2) ? ONEONE : 0u, 0u, 0u, 0u);
                u1.q = u0.q;
            }
            a1f0 = u0.v;
            a1f1 = u1.v;
        }

        // per-lane B-fragment pointer + per-jt stride (dwords)
        const unsigned int* bptr;
        int bstride;
        if (quad < 2)       { bptr = &BH[tt][off(l15) + qh * 4]; bstride = 144; }
        else if (quad == 2) { bptr = &BG[tt][l15 * 4];           bstride = 64;  }
        else                { bptr = &zero4[0];                  bstride = 0;   }

        float s00 = 0.f, s01 = 0.f, s02 = 0.f, s03 = 0.f;
        float s10 = 0.f, s11 = 0.f, s12 = 0.f, s13 = 0.f;

        // pipelined main loop: MFMA tile jt, exp tile jt-1
        floatx4 accP0, accP1, accC0, accC1;
        {
            FragU b; b.q = *(const uint4*)bptr; bptr += bstride;
            floatx4 zc = {0.f, 0.f, 0.f, 0.f};
            accP0 = __builtin_amdgcn_mfma_f32_16x16x32_bf16(a1f0, b.v, zc, 0, 0, 0);
            accP1 = __builtin_amdgcn_mfma_f32_16x16x32_bf16(a1f1, b.v, zc, 0, 0, 0);
        }
#pragma unroll
        for (int jt = 1; jt < 8; ++jt) {
            FragU b; b.q = *(const uint4*)bptr; bptr += bstride;
            floatx4 zc = {0.f, 0.f, 0.f, 0.f};
            accC0 = __builtin_amdgcn_mfma_f32_16x16x32_bf16(a1f0, b.v, zc, 0, 0, 0);
            accC1 = __builtin_amdgcn_mfma_f32_16x16x32_bf16(a1f1, b.v, zc, 0, 0, 0);
            s00 += __builtin_amdgcn_exp2f(accP0[0]);
            s01 += __builtin_amdgcn_exp2f(accP0[1]);
            s02 += __builtin_amdgcn_exp2f(accP0[2]);
            s03 += __builtin_amdgcn_exp2f(accP0[3]);
            s10 += __builtin_amdgcn_exp2f(accP1[0]);
            s11 += __builtin_amdgcn_exp2f(accP1[1]);
            s12 += __builtin_amdgcn_exp2f(accP1[2]);
            s13 += __builtin_amdgcn_exp2f(accP1[3]);
            accP0 = accC0;
            accP1 = accC1;
        }
        s00 += __builtin_amdgcn_exp2f(accP0[0]);
        s01 += __builtin_amdgcn_exp2f(accP0[1]);
        s02 += __builtin_amdgcn_exp2f(accP0[2]);
        s03 += __builtin_amdgcn_exp2f(accP0[3]);
        s10 += __builtin_amdgcn_exp2f(accP1[0]);
        s11 += __builtin_amdgcn_exp2f(accP1[1]);
        s12 += __builtin_amdgcn_exp2f(accP1[2]);
        s13 += __builtin_amdgcn_exp2f(accP1[3]);

        // per-t epilogue: weighted row-scale into running total
        float wt = (t == 0 || t == 127) ? 1.f : 2.f;
        if (isxx && sq > sa) wt *= 2.f;
        const int rbase = w * 32 + quad * 4;
        tot = fmaf(s00, wt * __builtin_amdgcn_exp2f(-srg[tt][rbase + 0]),  tot);
        tot = fmaf(s01, wt * __builtin_amdgcn_exp2f(-srg[tt][rbase + 1]),  tot);
        tot = fmaf(s02, wt * __builtin_amdgcn_exp2f(-srg[tt][rbase + 2]),  tot);
        tot = fmaf(s03, wt * __builtin_amdgcn_exp2f(-srg[tt][rbase + 3]),  tot);
        tot = fmaf(s10, wt * __builtin_amdgcn_exp2f(-srg[tt][rbase + 16]), tot);
        tot = fmaf(s11, wt * __builtin_amdgcn_exp2f(-srg[tt][rbase + 17]), tot);
        tot = fmaf(s12, wt * __builtin_amdgcn_exp2f(-srg[tt][rbase + 18]), tot);
        tot = fmaf(s13, wt * __builtin_amdgcn_exp2f(-srg[tt][rbase + 19]), tot);
    }

    // ---- block reduction, one store per block ----
    for (int o = 32; o > 0; o >>= 1) tot += __shfl_down(tot, o, 64);
    if (lane == 0) red[w] = tot;
    __syncthreads();
    if (tid == 0)
        part[slot * 32 + blockIdx.y] = red[0] + red[1] + red[2] + red[3];
}

__global__ __launch_bounds__(256) void finalize_kernel(const float* __restrict__ part,
                                                       float* __restrict__ out) {
    const int tid = threadIdx.x;
    // part[slot*32+tg]: slots 0..15 xy -> [0,512); slots 16..25 xx -> [512,832)
    double vxy = (double)part[tid] + (double)part[256 + tid];
    double vxx = (double)part[512 + tid];
    if (tid < 64) vxx += (double)part[768 + tid];
    for (int o = 32; o > 0; o >>= 1) {
        vxx += __shfl_down(vxx, o, 64);
        vxy += __shfl_down(vxy, o, 64);
    }
    __shared__ double red[8];
    const int wid = tid >> 6;
    if ((tid & 63) == 0) { red[wid] = vxx; red[4 + wid] = vxy; }
    __syncthreads();
    if (tid == 0) {
        double sxx = red[0] + red[1] + red[2] + red[3];
        double sxy = red[4] + red[5] + red[6] + red[7];
        // diagonal entries (~1.0 each) included in sxx: subtract 254*512
        double e1 = (sxx - 254.0 * 512.0) / (254.0 * 512.0 * 511.0);
        double e2 = sxy / (254.0 * 512.0 * 512.0);
        out[0] = (float)(e1 - 2.0 * e2);
    }
}

extern "C" void kernel_launch(void* const* d_in, const int* in_sizes, int n_in,
                              void* d_out, int out_size, void* d_ws, size_t ws_size,
                              hipStream_t stream) {
    (void)in_sizes; (void)n_in; (void)out_size; (void)ws_size;
    const float* x = (const float*)d_in[0];
    const float* y = (const float*)d_in[1];
    float* out  = (float*)d_out;
    float* part = (float*)d_ws;   // 832 floats: [0,512) xy, [512,832) xx

    mmd_kernel<<<dim3(NSLOT, 32), dim3(256), 0, stream>>>(x, y, part);
    finalize_kernel<<<dim3(1), dim3(256), 0, stream>>>(part, out);
}